// Round 1
// baseline (906.627 us; speedup 1.0000x reference)
//
#include <hip/hip_runtime.h>
#include <cstdint>
#include <cstddef>

// ---------- types / helpers ----------
typedef uint16_t u16;
typedef __bf16 bf16x8 __attribute__((ext_vector_type(8)));
typedef short  s16x8  __attribute__((ext_vector_type(8)));
typedef float  f32x4  __attribute__((ext_vector_type(4)));

__device__ __forceinline__ u16 f2b(float f) {
    union { float f; uint32_t u; } v; v.f = f;
    uint32_t u = v.u;
    uint32_t r = (u + 0x7FFFu + ((u >> 16) & 1u)) >> 16;   // RNE truncate to bf16
    return (u16)r;
}
__device__ __forceinline__ float b2f(u16 h) {
    union { uint32_t u; float f; } v; v.u = ((uint32_t)h) << 16;
    return v.f;
}
__device__ __forceinline__ float leakyf(float x) { return x > 0.f ? x : 0.2f * x; }
__device__ __forceinline__ void unp4(uint2 u, float& f0, float& f1, float& f2, float& f3) {
    union { uint32_t u; float f; } t;
    t.u = u.x << 16;          f0 = t.f;
    t.u = u.x & 0xffff0000u;  f1 = t.f;
    t.u = u.y << 16;          f2 = t.f;
    t.u = u.y & 0xffff0000u;  f3 = t.f;
}

static constexpr int NN = 8000;      // nodes
static constexpr int EE = 512000;    // edges
static constexpr int BB = 8;         // batch

// global_load_lds: LDS dest is wave-uniform base + lane*16 (guide §5); global src per-lane.
#define GLOAD_LDS16(gp, lp)                                                              \
    __builtin_amdgcn_global_load_lds((const __attribute__((address_space(1))) void*)(gp), \
                                     (__attribute__((address_space(3))) void*)(lp), 16, 0, 0)

// ---------- weight transpose+convert: W[k][n] (f32) -> Bt[n][k] (bf16), n padded to 256 ----------
__global__ void conv_wT(const float* __restrict__ W, int Wn, int rows, int rowOff,
                        u16* __restrict__ Bt, int Kpad, int kOff, int kSpan) {
    __shared__ u16 tile[64][65];
    const int kb = blockIdx.x * 64, nb = blockIdx.y * 64;
    const int tid = threadIdx.x;
    const int ln = tid & 63, lw = tid >> 6;
    #pragma unroll
    for (int r = 0; r < 16; r++) {
        int kk = kb + lw * 16 + r;
        int n  = nb + ln;
        float v = (kk < rows && n < Wn) ? W[(size_t)(rowOff + kk) * Wn + n] : 0.f;
        tile[ln][lw * 16 + r] = f2b(v);
    }
    __syncthreads();
    #pragma unroll
    for (int r = 0; r < 16; r++) {
        int nl = lw * 16 + r;
        int kk = kb + ln;
        if (kk < kSpan) Bt[(size_t)(nb + nl) * Kpad + kOff + kk] = tile[nl][ln];
    }
}

// merged small transposes: z selects one of 5 (all 200x(<=256) weights), grid (4,4,5)
__global__ void conv_wT5(const float* W_mp2, const float* W_pl1, const float* W_g1, const float* W_g2,
                         u16* Btmp2, u16* Btpl1, u16* Btg1, u16* Btg2) {
    __shared__ u16 tile[64][65];
    const float* W; int Wn, rows, rowOff; u16* Bt; int Kpad, kOff, kSpan;
    switch (blockIdx.z) {
        case 0: W = W_mp2; Wn = 200; rows = 256; rowOff = 0;   Bt = Btmp2; Kpad = 256; kOff = 0;   kSpan = 256; break;
        case 1: W = W_pl1; Wn = 200; rows = 200; rowOff = 0;   Bt = Btpl1; Kpad = 512; kOff = 0;   kSpan = 256; break;
        case 2: W = W_pl1; Wn = 200; rows = 200; rowOff = 200; Bt = Btpl1; Kpad = 512; kOff = 256; kSpan = 256; break;
        case 3: W = W_g1;  Wn = 200; rows = 200; rowOff = 0;   Bt = Btg1;  Kpad = 256; kOff = 0;   kSpan = 256; break;
        default:W = W_g2;  Wn = 200; rows = 200; rowOff = 0;   Bt = Btg2;  Kpad = 256; kOff = 0;   kSpan = 256; break;
    }
    const int kb = blockIdx.x * 64, nb = blockIdx.y * 64;
    const int tid = threadIdx.x;
    const int ln = tid & 63, lw = tid >> 6;
    #pragma unroll
    for (int r = 0; r < 16; r++) {
        int kk = kb + lw * 16 + r;
        int n  = nb + ln;
        float v = (kk < rows && n < Wn) ? W[(size_t)(rowOff + kk) * Wn + n] : 0.f;
        tile[ln][lw * 16 + r] = f2b(v);
    }
    __syncthreads();
    #pragma unroll
    for (int r = 0; r < 16; r++) {
        int nl = lw * 16 + r;
        int kk = kb + ln;
        if (kk < kSpan) Bt[(size_t)(nb + nl) * Kpad + kOff + kk] = tile[nl][ln];
    }
}

// pad 5 bias vectors to 256 floats each in one launch (src may be null -> zeros)
__global__ void padvec5(const float* p0, int n0, float* d0,
                        const float* p1, int n1, float* d1,
                        const float* p2, int n2, float* d2,
                        const float* p3, int n3, float* d3,
                        const float* p4, int n4, float* d4) {
    const float* p; int n; float* d;
    switch (blockIdx.x) {
        case 0: p = p0; n = n0; d = d0; break;
        case 1: p = p1; n = n1; d = d1; break;
        case 2: p = p2; n = n2; d = d2; break;
        case 3: p = p3; n = n3; d = d3; break;
        default: p = p4; n = n4; d = d4; break;
    }
    int i = threadIdx.x;
    d[i] = (p != nullptr && i < n) ? p[i] : 0.f;
}

__global__ void zero_i32(int* __restrict__ p, int n) {
    int i = blockIdx.x * 256 + threadIdx.x;
    if (i < n) p[i] = 0;
}

// ---------- MFMA GEMM: C[M,256] = A[M,K] @ Bt[256,K]^T (+ bias) ----------
// BM=32, BN=256 (full width), BK=64. 256 threads = 4 waves, wave w -> cols [64w,64w+64).
// 2-phase double-buffered pipeline (guide T3-minimum):
//   - B staged direct-to-LDS via global_load_lds (width 16), linear layout with
//     XOR granule swizzle applied to the GLOBAL source address (m173 pattern):
//     16B-granule g of row r lands at LDS slot g, holding data of source granule
//     g ^ (r&7); the b-frag read XORs the same way -> 2-way banked (free).
//   - A reg-staged with async split (T14): issue next tile's global loads at phase
//     start, cvt+ds_write after the MFMA phase (HBM latency hides under compute).
//   - One __syncthreads per K-step; its implicit vmcnt(0) drains the B loads,
//     which had the whole compute phase to land.
// Split-K via grid.y (kLen per split, f32 partials).
// cmode: 0 = f32 out (+bias), 1 = bf16 out (+bias), 2 = f32 partial (no bias)
__global__ __launch_bounds__(256) void gemm_kernel(
    const void* __restrict__ Ap, int a_is_f32, int lda,
    const u16* __restrict__ Bt, int K, int kLen,
    const float* __restrict__ bias,
    void* __restrict__ Cp, int cmode, int ldc, int do_leaky, size_t partStride) {
    __shared__ u16 As[2][32][72];          // padded (144B row): a-frag reads conflict-free
    __shared__ u16 Bs[2][16384];           // linear 256x64 bf16, source-swizzled granules
    const int tid  = threadIdx.x;
    const int m0   = blockIdx.x * 32;
    const int kStart = blockIdx.y * kLen;
    const int wave = tid >> 6, lane = tid & 63;
    const int q = lane >> 4, r = lane & 15;
    const int wn = wave * 64;
    const int arow = tid & 31, akoff = (tid >> 5) * 8;   // A staging: 8 elems/thread
    const int nIter = kLen >> 6;

    f32x4 acc[2][4];
    #pragma unroll
    for (int i = 0; i < 2; i++)
        #pragma unroll
        for (int j = 0; j < 4; j++) acc[i][j] = (f32x4){0, 0, 0, 0};

    // --- staging helpers ---
    auto stageB = [&](int buf, int k0) {            // 8 global_load_lds per wave
        #pragma unroll
        for (int c = 0; c < 8; ++c) {
            const int idx16 = c * 256 + tid;        // granule index 0..2047
            const int row   = idx16 >> 3;           // 8 granules (128B) per row
            const int gs    = (idx16 & 7) ^ (row & 7);   // pre-swizzled source granule
            const u16* src  = Bt + (size_t)row * K + k0 + gs * 8;
            u16* dst = &Bs[buf][0] + c * 2048 + wave * 512;   // wave-uniform base
            GLOAD_LDS16(src, dst);
        }
    };
    float4 fa0, fa1; uint4 ua;
    auto loadA = [&](int k0) {                      // issue only (regs)
        if (a_is_f32) {
            const float* A = (const float*)Ap + (size_t)(m0 + arow) * lda + k0 + akoff;
            fa0 = *(const float4*)A;
            fa1 = *(const float4*)(A + 4);
        } else {
            const u16* A = (const u16*)Ap + (size_t)(m0 + arow) * lda + k0 + akoff;
            ua = *(const uint4*)A;
        }
    };
    auto writeA = [&](int buf) {                    // cvt + ds_write (waits A vmcnt only)
        uint4 w;
        if (a_is_f32) {
            u16 h[8];
            h[0] = f2b(fa0.x); h[1] = f2b(fa0.y); h[2] = f2b(fa0.z); h[3] = f2b(fa0.w);
            h[4] = f2b(fa1.x); h[5] = f2b(fa1.y); h[6] = f2b(fa1.z); h[7] = f2b(fa1.w);
            w = *(uint4*)h;
        } else w = ua;
        *(uint4*)(&As[buf][arow][akoff]) = w;
    };

    // --- prologue: stage tile 0 ---
    loadA(kStart);        // A first (so its vmcnt wait later doesn't drain B)
    stageB(0, kStart);
    writeA(0);
    __syncthreads();      // drains vmcnt(0): Bs[0] ready

    int cur = 0;
    for (int t = 0; t < nIter; ++t) {
        const int nb = cur ^ 1;
        const bool hasNext = (t + 1 < nIter);
        if (hasNext) {
            const int k1 = kStart + (t + 1) * 64;
            loadA(k1);            // async issue into regs
            stageB(nb, k1);       // async issue direct-to-LDS
        }
        const char* BsC = (const char*)&Bs[cur][0];
        #pragma unroll
        for (int ks = 0; ks < 2; ks++) {
            const int kb = ks * 32 + q * 8;
            s16x8 a0 = *(const s16x8*)(&As[cur][r][kb]);
            s16x8 a1 = *(const s16x8*)(&As[cur][16 + r][kb]);
            const int swz  = ((ks << 2) + q) ^ (r & 7);            // granule XOR read
            const int boff = ((wn + r) << 7) + (swz << 4);         // bytes
            s16x8 b0 = *(const s16x8*)(BsC + boff);
            s16x8 b1 = *(const s16x8*)(BsC + boff + 2048);
            s16x8 b2 = *(const s16x8*)(BsC + boff + 4096);
            s16x8 b3 = *(const s16x8*)(BsC + boff + 6144);
            acc[0][0] = __builtin_amdgcn_mfma_f32_16x16x32_bf16(__builtin_bit_cast(bf16x8, a0), __builtin_bit_cast(bf16x8, b0), acc[0][0], 0, 0, 0);
            acc[0][1] = __builtin_amdgcn_mfma_f32_16x16x32_bf16(__builtin_bit_cast(bf16x8, a0), __builtin_bit_cast(bf16x8, b1), acc[0][1], 0, 0, 0);
            acc[0][2] = __builtin_amdgcn_mfma_f32_16x16x32_bf16(__builtin_bit_cast(bf16x8, a0), __builtin_bit_cast(bf16x8, b2), acc[0][2], 0, 0, 0);
            acc[0][3] = __builtin_amdgcn_mfma_f32_16x16x32_bf16(__builtin_bit_cast(bf16x8, a0), __builtin_bit_cast(bf16x8, b3), acc[0][3], 0, 0, 0);
            acc[1][0] = __builtin_amdgcn_mfma_f32_16x16x32_bf16(__builtin_bit_cast(bf16x8, a1), __builtin_bit_cast(bf16x8, b0), acc[1][0], 0, 0, 0);
            acc[1][1] = __builtin_amdgcn_mfma_f32_16x16x32_bf16(__builtin_bit_cast(bf16x8, a1), __builtin_bit_cast(bf16x8, b1), acc[1][1], 0, 0, 0);
            acc[1][2] = __builtin_amdgcn_mfma_f32_16x16x32_bf16(__builtin_bit_cast(bf16x8, a1), __builtin_bit_cast(bf16x8, b2), acc[1][2], 0, 0, 0);
            acc[1][3] = __builtin_amdgcn_mfma_f32_16x16x32_bf16(__builtin_bit_cast(bf16x8, a1), __builtin_bit_cast(bf16x8, b3), acc[1][3], 0, 0, 0);
        }
        if (hasNext) writeA(nb);  // waits A loads (B's 8 stay outstanding), LDS write
        __syncthreads();          // drains B vmcnt + LDS; buffers swap safely
        cur = nb;
    }

    #pragma unroll
    for (int ti = 0; ti < 2; ti++)
        #pragma unroll
        for (int tj = 0; tj < 4; tj++)
            #pragma unroll
            for (int reg = 0; reg < 4; reg++) {
                int gr = m0 + ti * 16 + q * 4 + reg;   // C/D: row = quad*4+reg
                int gc = wn + tj * 16 + r;             //      col = lane&15
                float v = acc[ti][tj][reg];
                if (cmode == 2) {
                    ((float*)Cp)[blockIdx.y * partStride + (size_t)gr * 256 + gc] = v;
                } else {
                    v += bias[gc];
                    if (do_leaky) v = leakyf(v);
                    if (cmode == 1) ((u16*)Cp)[(size_t)gr * ldc + gc] = f2b(v);
                    else            ((float*)Cp)[(size_t)gr * ldc + gc] = v;
                }
            }
}

// ---------- split-K reduce ----------
__global__ void reduce_k(const float* __restrict__ part, size_t partStride, int S,
                         const float* __restrict__ bias, void* __restrict__ out,
                         int out_bf16, int ldc, int do_leaky) {
    int i = blockIdx.x * 256 + threadIdx.x;    // over NN*256
    float v = 0.f;
    for (int s = 0; s < S; s++) v += part[s * partStride + i];
    int col = i & 255, row = i >> 8;
    v += bias[col];
    if (do_leaky) v = leakyf(v);
    if (out_bf16) ((u16*)out)[(size_t)row * ldc + col] = f2b(v);
    else          ((float*)out)[(size_t)row * ldc + col] = v;
}

// ---------- graph build ----------
__global__ void count_kernel(const int* __restrict__ dst, int* __restrict__ cnt) {
    int e = blockIdx.x * 256 + threadIdx.x;
    if (e < EE) atomicAdd(&cnt[dst[e]], 1);
}
// scan + dinv fused (single block, 1024 threads)
__global__ void scan_kernel(const int* __restrict__ cnt, int* __restrict__ row_start,
                            int* __restrict__ cursor, float* __restrict__ dinv) {
    __shared__ int part[1024];
    const int tid = threadIdx.x;
    int local[8];
    int s = 0;
    const int base = tid * 8;
    #pragma unroll
    for (int j = 0; j < 8; j++) { int idx = base + j; int v = (idx < NN) ? cnt[idx] : 0; local[j] = s; s += v; }
    part[tid] = s;
    __syncthreads();
    for (int off = 1; off < 1024; off <<= 1) {
        int v = (tid >= off) ? part[tid - off] : 0;
        __syncthreads();
        part[tid] += v;
        __syncthreads();
    }
    const int excl = (tid == 0) ? 0 : part[tid - 1];
    #pragma unroll
    for (int j = 0; j < 8; j++) {
        int idx = base + j;
        if (idx < NN) {
            int v = excl + local[j];
            row_start[idx] = v; cursor[idx] = v;
            dinv[idx] = rsqrtf((float)cnt[idx] + 2.0f);
        }
    }
    if (tid == 1023) row_start[NN] = part[1023];
}
__global__ void fill_kernel(const int* __restrict__ src, const int* __restrict__ dst,
                            int* __restrict__ cursor, const float* __restrict__ dinv,
                            int* __restrict__ csr_src, float* __restrict__ csr_w) {
    int e = blockIdx.x * 256 + threadIdx.x;
    if (e < EE) {
        int s = src[e], d = dst[e];
        int pos = atomicAdd(&cursor[d], 1);
        csr_src[pos] = s;
        csr_w[pos]   = dinv[s] * dinv[d];
    }
}

// ---------- GCN aggregation: wave-per-node, 4 cols/lane, 8-deep pipelined gathers ----------
// out_bf16 != null : layer-1 mode, writes y1[NN][256] bf16 (cols>=200 zero), bias = g1_b (200 raw)
// out_bf16 == null : layer-2 mode, fused cosine+sigmoid vs dhat -> out_sig[NN]
__global__ __launch_bounds__(256) void agg_kernel(
    const u16* __restrict__ h, const float* __restrict__ dinv,
    const int* __restrict__ row_start, const int* __restrict__ csr_src,
    const float* __restrict__ csr_w, const float* __restrict__ bias,
    u16* __restrict__ out_bf16, const float* __restrict__ dhat,
    float* __restrict__ out_sig) {
    const int wave = threadIdx.x >> 6, lane = threadIdx.x & 63;
    const int node = blockIdx.x * 4 + wave;
    const int start = row_start[node], end = row_start[node + 1];
    const float di = dinv[node];

    float a0, a1, a2, a3;
    {   // self loop: 2*dinv^2 * h[node]
        uint2 hv = *(const uint2*)(h + (size_t)node * 256 + lane * 4);
        float f0, f1, f2, f3; unp4(hv, f0, f1, f2, f3);
        float sl = 2.f * di * di;
        a0 = sl * f0; a1 = sl * f1; a2 = sl * f2; a3 = sl * f3;
    }

    for (int p = start; p < end; p += 64) {
        const int n = min(64, end - p);
        int   mySrc = 0;
        float myW   = 0.f;
        if (lane < n) { mySrc = csr_src[p + lane]; myW = csr_w[p + lane]; }
        int j0 = 0;
        for (; j0 + 8 <= n; j0 += 8) {
            int sj[8]; float wj[8]; uint2 rj[8];
            #pragma unroll
            for (int j = 0; j < 8; j++) { sj[j] = __shfl(mySrc, j0 + j); wj[j] = __shfl(myW, j0 + j); }
            #pragma unroll
            for (int j = 0; j < 8; j++) rj[j] = *(const uint2*)(h + (size_t)sj[j] * 256 + lane * 4);
            #pragma unroll
            for (int j = 0; j < 8; j++) {
                float f0, f1, f2, f3; unp4(rj[j], f0, f1, f2, f3);
                a0 += wj[j] * f0; a1 += wj[j] * f1; a2 += wj[j] * f2; a3 += wj[j] * f3;
            }
        }
        for (; j0 < n; j0++) {
            int s = __shfl(mySrc, j0);
            float w = __shfl(myW, j0);
            uint2 rv = *(const uint2*)(h + (size_t)s * 256 + lane * 4);
            float f0, f1, f2, f3; unp4(rv, f0, f1, f2, f3);
            a0 += w * f0; a1 += w * f1; a2 += w * f2; a3 += w * f3;
        }
    }

    if (out_bf16 != nullptr) {
        uint2 o = {0u, 0u};
        if (lane < 50) {   // 50*4 = 200 real cols
            float4 bv = *(const float4*)(bias + lane * 4);
            u16 h0 = f2b(a0 + bv.x), h1 = f2b(a1 + bv.y), h2 = f2b(a2 + bv.z), h3 = f2b(a3 + bv.w);
            o.x = (uint32_t)h0 | ((uint32_t)h1 << 16);
            o.y = (uint32_t)h2 | ((uint32_t)h3 << 16);
        }
        *(uint2*)(out_bf16 + (size_t)node * 256 + lane * 4) = o;
    } else {
        float dot = 0.f, nn2 = 0.f;
        if (lane < 50) {
            float4 bv = *(const float4*)(bias + lane * 4);
            float4 dv = *(const float4*)(dhat + (node / 1000) * 200 + lane * 4);
            float v0 = a0 + bv.x, v1 = a1 + bv.y, v2 = a2 + bv.z, v3 = a3 + bv.w;
            dot = v0 * dv.x + v1 * dv.y + v2 * dv.z + v3 * dv.w;
            nn2 = v0 * v0 + v1 * v1 + v2 * v2 + v3 * v3;
        }
        #pragma unroll
        for (int off = 32; off; off >>= 1) {
            dot += __shfl_xor(dot, off, 64);
            nn2 += __shfl_xor(nn2, off, 64);
        }
        if (lane == 0) {
            float sim = dot / fmaxf(sqrtf(nn2), 1e-8f);
            out_sig[node] = 1.f / (1.f + expf(-sim));
        }
    }
}

// ---------- drug branch (tiny): one block per drug ----------
__global__ void drug_kernel(const float* __restrict__ drugF, const float* __restrict__ drugM,
                            const float* __restrict__ hW, const float* __restrict__ hb,
                            const float* __restrict__ m1W, const float* __restrict__ m1b,
                            const float* __restrict__ m2W, const float* __restrict__ m2b,
                            const float* __restrict__ l1W, const float* __restrict__ l1b,
                            const float* __restrict__ l2W, const float* __restrict__ l2b,
                            float* __restrict__ dhat) {
    const int b = blockIdx.x, tid = threadIdx.x;
    __shared__ float sF[1024], sM[1024], sT[256], s400[400], s200[200], sred[256];
    for (int k = tid; k < 1024; k += 256) { sF[k] = drugF[b * 1024 + k]; sM[k] = drugM[b * 1024 + k]; }
    __syncthreads();
    {
        float acc = m1b[tid];
        for (int k = 0; k < 1024; k++) acc += sM[k] * m1W[k * 256 + tid];
        sT[tid] = leakyf(acc);
    }
    float dfv = 0.f;
    if (tid < 200) {
        dfv = hb[tid];
        for (int k = 0; k < 1024; k++) dfv += sF[k] * hW[k * 200 + tid];
    }
    __syncthreads();
    if (tid < 200) {
        float acc = m2b[tid];
        for (int k = 0; k < 256; k++) acc += sT[k] * m2W[k * 200 + tid];
        s400[tid]       = leakyf(acc);
        s400[200 + tid] = leakyf(dfv);
    }
    __syncthreads();
    if (tid < 200) {
        float acc = l1b[tid];
        for (int k = 0; k < 400; k++) acc += s400[k] * l1W[k * 200 + tid];
        s200[tid] = leakyf(acc);
    }
    __syncthreads();
    float dv = 0.f;
    if (tid < 200) {
        dv = l2b[tid];
        for (int k = 0; k < 200; k++) dv += s200[k] * l2W[k * 200 + tid];
    }
    sred[tid] = (tid < 200) ? dv * dv : 0.f;
    __syncthreads();
    for (int off = 128; off; off >>= 1) {
        if (tid < off) sred[tid] += sred[tid + off];
        __syncthreads();
    }
    float nrm = fmaxf(sqrtf(sred[0]), 1e-8f);
    if (tid < 200) dhat[b * 200 + tid] = dv / nrm;
}

// ---------- launch ----------
extern "C" void kernel_launch(void* const* d_in, const int* in_sizes, int n_in,
                              void* d_out, int out_size, void* d_ws, size_t ws_size,
                              hipStream_t stream) {
    const float* PPI_x = (const float*)d_in[0];
    const float* PMF   = (const float*)d_in[1];
    const float* drugF = (const float*)d_in[2];
    const float* drugM = (const float*)d_in[3];
    const int*   eidx  = (const int*)d_in[4];
    const float* hpo_drug_W = (const float*)d_in[5];
    const float* hpo_drug_b = (const float*)d_in[6];
    const float* hpo_prot_W = (const float*)d_in[7];
    const float* hpo_prot_b = (const float*)d_in[8];
    const float* mp_W1 = (const float*)d_in[9];
    const float* mp_b1 = (const float*)d_in[10];
    const float* mp_W2 = (const float*)d_in[11];
    const float* mp_b2 = (const float*)d_in[12];
    const float* md_W1 = (const float*)d_in[13];
    const float* md_b1 = (const float*)d_in[14];
    const float* md_W2 = (const float*)d_in[15];
    const float* md_b2 = (const float*)d_in[16];
    const float* pl1_W = (const float*)d_in[17];
    const float* pl1_b = (const float*)d_in[18];
    const float* dl1_W = (const float*)d_in[19];
    const float* dl1_b = (const float*)d_in[20];
    const float* dl2_W = (const float*)d_in[21];
    const float* dl2_b = (const float*)d_in[22];
    const float* g1_W  = (const float*)d_in[23];
    const float* g1_b  = (const float*)d_in[24];
    const float* g2_W  = (const float*)d_in[25];
    const float* g2_b  = (const float*)d_in[26];

    char* wsp = (char*)d_ws;
    size_t off = 0;
    auto alloc = [&](size_t bytes) -> void* {
        size_t o = (off + 255) & ~(size_t)255;
        off = o + bytes;
        return (void*)(wsp + o);
    };

    u16* cb    = (u16*)alloc((size_t)NN * 512 * 2);   // leaky([px, pm])
    u16* t1    = (u16*)alloc((size_t)NN * 256 * 2);   // leaky(PMF@W1+b1); later y1
    u16* px2   = (u16*)alloc((size_t)NN * 256 * 2);
    u16* hbuf  = (u16*)alloc((size_t)NN * 256 * 2);
    float* part = (float*)alloc((size_t)2 * NN * 256 * 4);   // split-K partials (S=2)
    u16* Btmp1 = (u16*)alloc((size_t)256 * 8192 * 2);
    u16* Bthpo = (u16*)alloc((size_t)256 * 1024 * 2);
    u16* Btmp2 = (u16*)alloc((size_t)256 * 256 * 2);
    u16* Btpl1 = (u16*)alloc((size_t)256 * 512 * 2);
    u16* Btg1  = (u16*)alloc((size_t)256 * 256 * 2);
    u16* Btg2  = (u16*)alloc((size_t)256 * 256 * 2);
    float* bias_hpo = (float*)alloc(256 * 4);
    float* bias_m1  = (float*)alloc(256 * 4);
    float* bias_m2  = (float*)alloc(256 * 4);
    float* bias_pl  = (float*)alloc(256 * 4);
    float* zero256  = (float*)alloc(256 * 4);
    float* dhat     = (float*)alloc((size_t)BB * 200 * 4);
    int*   deg      = (int*)alloc((size_t)NN * 4);
    float* dinv     = (float*)alloc((size_t)NN * 4);
    int*   row_st   = (int*)alloc((size_t)(NN + 4) * 4);
    int*   cursor   = (int*)alloc((size_t)NN * 4);
    int*   csr_src  = (int*)alloc((size_t)EE * 4);
    float* csr_w    = (float*)alloc((size_t)EE * 4);

    u16* y1 = t1;           // alias (t1 dead after G3)
    const size_t PSTRIDE = (size_t)NN * 256;

    const int* e_src = eidx;
    const int* e_dst = eidx + EE;

    // weight conversions
    conv_wT<<<dim3(16, 4),  256, 0, stream>>>(hpo_prot_W, 200, 1024, 0, Bthpo, 1024, 0, 1024);
    conv_wT<<<dim3(128, 4), 256, 0, stream>>>(mp_W1,      256, 8192, 0, Btmp1, 8192, 0, 8192);
    conv_wT5<<<dim3(4, 4, 5), 256, 0, stream>>>(mp_W2, pl1_W, g1_W, g2_W, Btmp2, Btpl1, Btg1, Btg2);
    padvec5<<<5, 256, 0, stream>>>(hpo_prot_b, 200, bias_hpo,
                                   mp_b1,      256, bias_m1,
                                   mp_b2,      200, bias_m2,
                                   pl1_b,      200, bias_pl,
                                   nullptr,    0,   zero256);

    // drug branch
    drug_kernel<<<BB, 256, 0, stream>>>(drugF, drugM, hpo_drug_W, hpo_drug_b,
                                        md_W1, md_b1, md_W2, md_b2,
                                        dl1_W, dl1_b, dl2_W, dl2_b, dhat);

    const int MB = NN / 32;            // 250
    const int RG = (NN * 256) / 256;   // reduce grid

    // G1: cb[:,0:256] = leaky(PPI_x @ hpo_prot_W + b)   (K=1024, no split -> direct bf16 out)
    gemm_kernel<<<dim3(MB, 1), 256, 0, stream>>>(PPI_x, 1, 1024, Bthpo, 1024, 1024, bias_hpo, cb, 1, 512, 1, 0);
    // G2: t1 = leaky(PMF @ mp_W1 + b1)   (K=8192, split-K=2)
    gemm_kernel<<<dim3(MB, 2), 256, 0, stream>>>(PMF, 1, 8192, Btmp1, 8192, 4096, zero256, part, 2, 256, 0, PSTRIDE);
    reduce_k<<<RG, 256, 0, stream>>>(part, PSTRIDE, 2, bias_m1, t1, 1, 256, 1);
    // G3: cb[:,256:512] = leaky(t1 @ mp_W2 + b2)   (K=256)
    gemm_kernel<<<dim3(MB, 1), 256, 0, stream>>>(t1, 0, 256, Btmp2, 256, 256, bias_m2, cb + 256, 1, 512, 1, 0);
    // G4: px2 = cb @ pl1_W + pl1_b   (K=512)
    gemm_kernel<<<dim3(MB, 1), 256, 0, stream>>>(cb, 0, 512, Btpl1, 512, 512, bias_pl, px2, 1, 256, 0, 0);

    // graph build
    zero_i32<<<(NN + 255) / 256, 256, 0, stream>>>(deg, NN);
    count_kernel<<<EE / 256, 256, 0, stream>>>(e_dst, deg);
    scan_kernel<<<1, 1024, 0, stream>>>(deg, row_st, cursor, dinv);
    fill_kernel<<<EE / 256, 256, 0, stream>>>(e_src, e_dst, cursor, dinv, csr_src, csr_w);

    // GCN layer 1
    gemm_kernel<<<dim3(MB, 1), 256, 0, stream>>>(px2, 0, 256, Btg1, 256, 256, zero256, hbuf, 1, 256, 0, 0);
    agg_kernel<<<NN / 4, 256, 0, stream>>>(hbuf, dinv, row_st, csr_src, csr_w, g1_b, y1, nullptr, nullptr);
    // GCN layer 2 + fused cosine/sigmoid
    gemm_kernel<<<dim3(MB, 1), 256, 0, stream>>>(y1, 0, 256, Btg2, 256, 256, zero256, hbuf, 1, 256, 0, 0);
    agg_kernel<<<NN / 4, 256, 0, stream>>>(hbuf, dinv, row_st, csr_src, csr_w, g2_b, nullptr, dhat, (float*)d_out);
}

// Round 2
// 899.476 us; speedup vs baseline: 1.0080x; 1.0080x over previous
//
#include <hip/hip_runtime.h>
#include <cstdint>
#include <cstddef>

// ---------- types / helpers ----------
typedef uint16_t u16;
typedef __bf16 bf16x8 __attribute__((ext_vector_type(8)));
typedef short  s16x8  __attribute__((ext_vector_type(8)));
typedef float  f32x4  __attribute__((ext_vector_type(4)));

__device__ __forceinline__ u16 f2b(float f) {
    union { float f; uint32_t u; } v; v.f = f;
    uint32_t u = v.u;
    uint32_t r = (u + 0x7FFFu + ((u >> 16) & 1u)) >> 16;   // RNE truncate to bf16
    return (u16)r;
}
__device__ __forceinline__ float b2f(u16 h) {
    union { uint32_t u; float f; } v; v.u = ((uint32_t)h) << 16;
    return v.f;
}
__device__ __forceinline__ float leakyf(float x) { return x > 0.f ? x : 0.2f * x; }
__device__ __forceinline__ void unp4(uint2 u, float& f0, float& f1, float& f2, float& f3) {
    union { uint32_t u; float f; } t;
    t.u = u.x << 16;          f0 = t.f;
    t.u = u.x & 0xffff0000u;  f1 = t.f;
    t.u = u.y << 16;          f2 = t.f;
    t.u = u.y & 0xffff0000u;  f3 = t.f;
}

static constexpr int NN = 8000;      // nodes
static constexpr int EE = 512000;    // edges
static constexpr int BB = 8;         // batch

// global_load_lds: LDS dest is wave-uniform base + lane*16 (guide §5); global src per-lane.
#define GLOAD_LDS16(gp, lp)                                                              \
    __builtin_amdgcn_global_load_lds((const __attribute__((address_space(1))) void*)(gp), \
                                     (__attribute__((address_space(3))) void*)(lp), 16, 0, 0)

// ---------- weight transpose+convert: W[k][n] (f32) -> Bt[n][k] (bf16), n padded to 256 ----------
__global__ void conv_wT(const float* __restrict__ W, int Wn, int rows, int rowOff,
                        u16* __restrict__ Bt, int Kpad, int kOff, int kSpan) {
    __shared__ u16 tile[64][65];
    const int kb = blockIdx.x * 64, nb = blockIdx.y * 64;
    const int tid = threadIdx.x;
    const int ln = tid & 63, lw = tid >> 6;
    #pragma unroll
    for (int r = 0; r < 16; r++) {
        int kk = kb + lw * 16 + r;
        int n  = nb + ln;
        float v = (kk < rows && n < Wn) ? W[(size_t)(rowOff + kk) * Wn + n] : 0.f;
        tile[ln][lw * 16 + r] = f2b(v);
    }
    __syncthreads();
    #pragma unroll
    for (int r = 0; r < 16; r++) {
        int nl = lw * 16 + r;
        int kk = kb + ln;
        if (kk < kSpan) Bt[(size_t)(nb + nl) * Kpad + kOff + kk] = tile[nl][ln];
    }
}

// merged small transposes: z selects one of 5 (all 200x(<=256) weights), grid (4,4,5)
__global__ void conv_wT5(const float* W_mp2, const float* W_pl1, const float* W_g1, const float* W_g2,
                         u16* Btmp2, u16* Btpl1, u16* Btg1, u16* Btg2) {
    __shared__ u16 tile[64][65];
    const float* W; int Wn, rows, rowOff; u16* Bt; int Kpad, kOff, kSpan;
    switch (blockIdx.z) {
        case 0: W = W_mp2; Wn = 200; rows = 256; rowOff = 0;   Bt = Btmp2; Kpad = 256; kOff = 0;   kSpan = 256; break;
        case 1: W = W_pl1; Wn = 200; rows = 200; rowOff = 0;   Bt = Btpl1; Kpad = 512; kOff = 0;   kSpan = 256; break;
        case 2: W = W_pl1; Wn = 200; rows = 200; rowOff = 200; Bt = Btpl1; Kpad = 512; kOff = 256; kSpan = 256; break;
        case 3: W = W_g1;  Wn = 200; rows = 200; rowOff = 0;   Bt = Btg1;  Kpad = 256; kOff = 0;   kSpan = 256; break;
        default:W = W_g2;  Wn = 200; rows = 200; rowOff = 0;   Bt = Btg2;  Kpad = 256; kOff = 0;   kSpan = 256; break;
    }
    const int kb = blockIdx.x * 64, nb = blockIdx.y * 64;
    const int tid = threadIdx.x;
    const int ln = tid & 63, lw = tid >> 6;
    #pragma unroll
    for (int r = 0; r < 16; r++) {
        int kk = kb + lw * 16 + r;
        int n  = nb + ln;
        float v = (kk < rows && n < Wn) ? W[(size_t)(rowOff + kk) * Wn + n] : 0.f;
        tile[ln][lw * 16 + r] = f2b(v);
    }
    __syncthreads();
    #pragma unroll
    for (int r = 0; r < 16; r++) {
        int nl = lw * 16 + r;
        int kk = kb + ln;
        if (kk < kSpan) Bt[(size_t)(nb + nl) * Kpad + kOff + kk] = tile[nl][ln];
    }
}

// pad 5 bias vectors to 256 floats each in one launch (src may be null -> zeros)
__global__ void padvec5(const float* p0, int n0, float* d0,
                        const float* p1, int n1, float* d1,
                        const float* p2, int n2, float* d2,
                        const float* p3, int n3, float* d3,
                        const float* p4, int n4, float* d4) {
    const float* p; int n; float* d;
    switch (blockIdx.x) {
        case 0: p = p0; n = n0; d = d0; break;
        case 1: p = p1; n = n1; d = d1; break;
        case 2: p = p2; n = n2; d = d2; break;
        case 3: p = p3; n = n3; d = d3; break;
        default: p = p4; n = n4; d = d4; break;
    }
    int i = threadIdx.x;
    d[i] = (p != nullptr && i < n) ? p[i] : 0.f;
}

__global__ void zero_i32(int* __restrict__ p, int n) {
    int i = blockIdx.x * 256 + threadIdx.x;
    if (i < n) p[i] = 0;
}

// ---------- MFMA GEMM: C[M,256] = A[M,K] @ Bt[256,K]^T (+ bias) ----------
// BM=32, BN=256 (full width), BK=64. 256 threads = 4 waves, wave w -> cols [64w,64w+64).
// T4 drain-free pipeline: raw s_barrier + counted s_waitcnt vmcnt(N); the barrier
// NEVER drains vmcnt to 0 in steady state. Per iteration (compute P, prefetch Q):
//   issue A(t+2) regs [depth-2] + 8x global_load_lds B(t+1)  -> 10 (f32 A) / 9 (bf16 A) newest
//   s_waitcnt vmcnt(KEEP)   // drains only B(t) (+A(t+1) regs), keeps the 10 newest in flight
//   s_barrier; sched_barrier(0)
//   MFMA on P
//   ds_write A(t+1) into As[Q] (loads already drained - no stall)
//   s_waitcnt lgkmcnt(0); s_barrier      // protects Q overwrite + As[Q] visibility
// B staged via global_load_lds w16, linear LDS, XOR-granule swizzle on the GLOBAL
// source address (m173); b-frag reads apply the same XOR -> ~2-way banked.
// Split-K via grid.y. cmode: 0=f32 out(+bias), 1=bf16 out(+bias), 2=f32 partial.
__global__ __launch_bounds__(256) void gemm_kernel(
    const void* __restrict__ Ap, int a_is_f32, int lda,
    const u16* __restrict__ Bt, int K, int kLen,
    const float* __restrict__ bias,
    void* __restrict__ Cp, int cmode, int ldc, int do_leaky, size_t partStride) {
    __shared__ u16 As[2][32][72];          // padded rows: a-frag reads conflict-free
    __shared__ u16 Bs[2][16384];           // linear 256x64 bf16, source-swizzled granules
    const int tid  = threadIdx.x;
    const int m0   = blockIdx.x * 32;
    const int kStart = blockIdx.y * kLen;
    const int wave = tid >> 6, lane = tid & 63;
    const int q = lane >> 4, r = lane & 15;
    const int wn = wave * 64;
    const int arow = tid & 31, akoff = (tid >> 5) * 8;   // A staging: 8 elems/thread
    const int n = kLen >> 6;               // iterations; always even (>=4) in our launches

    f32x4 acc[2][4];
    #pragma unroll
    for (int i = 0; i < 2; i++)
        #pragma unroll
        for (int j = 0; j < 4; j++) acc[i][j] = (f32x4){0, 0, 0, 0};

    auto stageB = [&](int buf, int k0) {            // 8 global_load_lds per wave
        #pragma unroll
        for (int c = 0; c < 8; ++c) {
            const int idx16 = c * 256 + tid;        // granule index 0..2047
            const int row   = idx16 >> 3;           // 8 granules (128B) per row
            const int gs    = (idx16 & 7) ^ (row & 7);   // pre-swizzled source granule
            const u16* src  = Bt + (size_t)row * K + k0 + gs * 8;
            u16* dst = &Bs[buf][0] + c * 2048 + wave * 512;   // wave-uniform base
            GLOAD_LDS16(src, dst);
        }
    };

    // two named A reg sets (depth-2 prefetch; static names per rule #20)
    float4 f0a, f1a, f0b, f1b; uint4 uA, uB;
    auto issueA_set0 = [&](int k0) {
        if (a_is_f32) {
            const float* A = (const float*)Ap + (size_t)(m0 + arow) * lda + k0 + akoff;
            f0a = *(const float4*)A; f1a = *(const float4*)(A + 4);
        } else {
            const u16* A = (const u16*)Ap + (size_t)(m0 + arow) * lda + k0 + akoff;
            uA = *(const uint4*)A;
        }
    };
    auto issueA_set1 = [&](int k0) {
        if (a_is_f32) {
            const float* A = (const float*)Ap + (size_t)(m0 + arow) * lda + k0 + akoff;
            f0b = *(const float4*)A; f1b = *(const float4*)(A + 4);
        } else {
            const u16* A = (const u16*)Ap + (size_t)(m0 + arow) * lda + k0 + akoff;
            uB = *(const uint4*)A;
        }
    };
    auto writeA_set0 = [&](int buf) {
        uint4 w;
        if (a_is_f32) {
            u16 h[8];
            h[0] = f2b(f0a.x); h[1] = f2b(f0a.y); h[2] = f2b(f0a.z); h[3] = f2b(f0a.w);
            h[4] = f2b(f1a.x); h[5] = f2b(f1a.y); h[6] = f2b(f1a.z); h[7] = f2b(f1a.w);
            w = *(uint4*)h;
        } else w = uA;
        *(uint4*)(&As[buf][arow][akoff]) = w;
    };
    auto writeA_set1 = [&](int buf) {
        uint4 w;
        if (a_is_f32) {
            u16 h[8];
            h[0] = f2b(f0b.x); h[1] = f2b(f0b.y); h[2] = f2b(f0b.z); h[3] = f2b(f0b.w);
            h[4] = f2b(f1b.x); h[5] = f2b(f1b.y); h[6] = f2b(f1b.z); h[7] = f2b(f1b.w);
            w = *(uint4*)h;
        } else w = uB;
        *(uint4*)(&As[buf][arow][akoff]) = w;
    };

#define GEMM_WAIT(hasA, hasB)                                                                   \
    do {                                                                                        \
        if (hasA) {                                                                             \
            if (a_is_f32) asm volatile("s_waitcnt vmcnt(10) lgkmcnt(0)" ::: "memory");           \
            else          asm volatile("s_waitcnt vmcnt(9) lgkmcnt(0)"  ::: "memory");           \
        } else if (hasB)  asm volatile("s_waitcnt vmcnt(8) lgkmcnt(0)"  ::: "memory");           \
        else              asm volatile("s_waitcnt vmcnt(0) lgkmcnt(0)"  ::: "memory");           \
    } while (0)

#define MFMA_PHASE(CUR)                                                                         \
    do {                                                                                        \
        const char* BsC = (const char*)&Bs[CUR][0];                                             \
        _Pragma("unroll")                                                                       \
        for (int ks = 0; ks < 2; ks++) {                                                        \
            const int kb = ks * 32 + q * 8;                                                     \
            s16x8 a0 = *(const s16x8*)(&As[CUR][r][kb]);                                        \
            s16x8 a1 = *(const s16x8*)(&As[CUR][16 + r][kb]);                                   \
            const int swz  = ((ks << 2) + q) ^ (r & 7);                                         \
            const int boff = ((wn + r) << 7) + (swz << 4);                                      \
            s16x8 b0 = *(const s16x8*)(BsC + boff);                                             \
            s16x8 b1 = *(const s16x8*)(BsC + boff + 2048);                                      \
            s16x8 b2 = *(const s16x8*)(BsC + boff + 4096);                                      \
            s16x8 b3 = *(const s16x8*)(BsC + boff + 6144);                                      \
            acc[0][0] = __builtin_amdgcn_mfma_f32_16x16x32_bf16(__builtin_bit_cast(bf16x8, a0), __builtin_bit_cast(bf16x8, b0), acc[0][0], 0, 0, 0); \
            acc[0][1] = __builtin_amdgcn_mfma_f32_16x16x32_bf16(__builtin_bit_cast(bf16x8, a0), __builtin_bit_cast(bf16x8, b1), acc[0][1], 0, 0, 0); \
            acc[0][2] = __builtin_amdgcn_mfma_f32_16x16x32_bf16(__builtin_bit_cast(bf16x8, a0), __builtin_bit_cast(bf16x8, b2), acc[0][2], 0, 0, 0); \
            acc[0][3] = __builtin_amdgcn_mfma_f32_16x16x32_bf16(__builtin_bit_cast(bf16x8, a0), __builtin_bit_cast(bf16x8, b3), acc[0][3], 0, 0, 0); \
            acc[1][0] = __builtin_amdgcn_mfma_f32_16x16x32_bf16(__builtin_bit_cast(bf16x8, a1), __builtin_bit_cast(bf16x8, b0), acc[1][0], 0, 0, 0); \
            acc[1][1] = __builtin_amdgcn_mfma_f32_16x16x32_bf16(__builtin_bit_cast(bf16x8, a1), __builtin_bit_cast(bf16x8, b1), acc[1][1], 0, 0, 0); \
            acc[1][2] = __builtin_amdgcn_mfma_f32_16x16x32_bf16(__builtin_bit_cast(bf16x8, a1), __builtin_bit_cast(bf16x8, b2), acc[1][2], 0, 0, 0); \
            acc[1][3] = __builtin_amdgcn_mfma_f32_16x16x32_bf16(__builtin_bit_cast(bf16x8, a1), __builtin_bit_cast(bf16x8, b3), acc[1][3], 0, 0, 0); \
        }                                                                                       \
    } while (0)

    // --- prologue: tile0 -> set0/buf0, tile1 A -> set1 ---
    issueA_set0(kStart);
    stageB(0, kStart);
    if (n > 1) issueA_set1(kStart + 64);
    writeA_set0(0);   // compiler auto-waits A(0) loads only; B(0)+A(1) stay in flight

    for (int t = 0; t < n; t += 2) {
        {   // ---- even body: compute buf0, prefetch buf1; write A(t+1) from set1 ----
            const bool hasA = t + 2 < n, hasB = t + 1 < n;
            if (hasA) issueA_set0(kStart + (t + 2) * 64);
            if (hasB) stageB(1, kStart + (t + 1) * 64);
            GEMM_WAIT(hasA, hasB);
            __builtin_amdgcn_s_barrier();
            __builtin_amdgcn_sched_barrier(0);
            MFMA_PHASE(0);
            if (hasB) writeA_set1(1);
            asm volatile("s_waitcnt lgkmcnt(0)" ::: "memory");
            __builtin_amdgcn_s_barrier();
        }
        {   // ---- odd body: compute buf1, prefetch buf0; write A(t+2) from set0 ----
            const bool hasA = t + 3 < n, hasB = t + 2 < n;
            if (hasA) issueA_set1(kStart + (t + 3) * 64);
            if (hasB) stageB(0, kStart + (t + 2) * 64);
            GEMM_WAIT(hasA, hasB);
            __builtin_amdgcn_s_barrier();
            __builtin_amdgcn_sched_barrier(0);
            MFMA_PHASE(1);
            if (hasB) writeA_set0(0);
            asm volatile("s_waitcnt lgkmcnt(0)" ::: "memory");
            __builtin_amdgcn_s_barrier();
        }
    }
#undef GEMM_WAIT
#undef MFMA_PHASE

    #pragma unroll
    for (int ti = 0; ti < 2; ti++)
        #pragma unroll
        for (int tj = 0; tj < 4; tj++)
            #pragma unroll
            for (int reg = 0; reg < 4; reg++) {
                int gr = m0 + ti * 16 + q * 4 + reg;   // C/D: row = quad*4+reg
                int gc = wn + tj * 16 + r;             //      col = lane&15
                float v = acc[ti][tj][reg];
                if (cmode == 2) {
                    ((float*)Cp)[blockIdx.y * partStride + (size_t)gr * 256 + gc] = v;
                } else {
                    v += bias[gc];
                    if (do_leaky) v = leakyf(v);
                    if (cmode == 1) ((u16*)Cp)[(size_t)gr * ldc + gc] = f2b(v);
                    else            ((float*)Cp)[(size_t)gr * ldc + gc] = v;
                }
            }
}

// ---------- split-K reduce ----------
__global__ void reduce_k(const float* __restrict__ part, size_t partStride, int S,
                         const float* __restrict__ bias, void* __restrict__ out,
                         int out_bf16, int ldc, int do_leaky) {
    int i = blockIdx.x * 256 + threadIdx.x;    // over NN*256
    float v = 0.f;
    for (int s = 0; s < S; s++) v += part[s * partStride + i];
    int col = i & 255, row = i >> 8;
    v += bias[col];
    if (do_leaky) v = leakyf(v);
    if (out_bf16) ((u16*)out)[(size_t)row * ldc + col] = f2b(v);
    else          ((float*)out)[(size_t)row * ldc + col] = v;
}

// ---------- graph build ----------
__global__ void count_kernel(const int* __restrict__ dst, int* __restrict__ cnt) {
    int e = blockIdx.x * 256 + threadIdx.x;
    if (e < EE) atomicAdd(&cnt[dst[e]], 1);
}
// scan + dinv fused (single block, 1024 threads)
__global__ void scan_kernel(const int* __restrict__ cnt, int* __restrict__ row_start,
                            int* __restrict__ cursor, float* __restrict__ dinv) {
    __shared__ int part[1024];
    const int tid = threadIdx.x;
    int local[8];
    int s = 0;
    const int base = tid * 8;
    #pragma unroll
    for (int j = 0; j < 8; j++) { int idx = base + j; int v = (idx < NN) ? cnt[idx] : 0; local[j] = s; s += v; }
    part[tid] = s;
    __syncthreads();
    for (int off = 1; off < 1024; off <<= 1) {
        int v = (tid >= off) ? part[tid - off] : 0;
        __syncthreads();
        part[tid] += v;
        __syncthreads();
    }
    const int excl = (tid == 0) ? 0 : part[tid - 1];
    #pragma unroll
    for (int j = 0; j < 8; j++) {
        int idx = base + j;
        if (idx < NN) {
            int v = excl + local[j];
            row_start[idx] = v; cursor[idx] = v;
            dinv[idx] = rsqrtf((float)cnt[idx] + 2.0f);
        }
    }
    if (tid == 1023) row_start[NN] = part[1023];
}
__global__ void fill_kernel(const int* __restrict__ src, const int* __restrict__ dst,
                            int* __restrict__ cursor, const float* __restrict__ dinv,
                            int* __restrict__ csr_src, float* __restrict__ csr_w) {
    int e = blockIdx.x * 256 + threadIdx.x;
    if (e < EE) {
        int s = src[e], d = dst[e];
        int pos = atomicAdd(&cursor[d], 1);
        csr_src[pos] = s;
        csr_w[pos]   = dinv[s] * dinv[d];
    }
}

// ---------- GCN aggregation: wave-per-node, 4 cols/lane, 8-deep pipelined gathers ----------
// out_bf16 != null : layer-1 mode, writes y1[NN][256] bf16 (cols>=200 zero), bias = g1_b (200 raw)
// out_bf16 == null : layer-2 mode, fused cosine+sigmoid vs dhat -> out_sig[NN]
__global__ __launch_bounds__(256) void agg_kernel(
    const u16* __restrict__ h, const float* __restrict__ dinv,
    const int* __restrict__ row_start, const int* __restrict__ csr_src,
    const float* __restrict__ csr_w, const float* __restrict__ bias,
    u16* __restrict__ out_bf16, const float* __restrict__ dhat,
    float* __restrict__ out_sig) {
    const int wave = threadIdx.x >> 6, lane = threadIdx.x & 63;
    const int node = blockIdx.x * 4 + wave;
    const int start = row_start[node], end = row_start[node + 1];
    const float di = dinv[node];

    float a0, a1, a2, a3;
    {   // self loop: 2*dinv^2 * h[node]
        uint2 hv = *(const uint2*)(h + (size_t)node * 256 + lane * 4);
        float f0, f1, f2, f3; unp4(hv, f0, f1, f2, f3);
        float sl = 2.f * di * di;
        a0 = sl * f0; a1 = sl * f1; a2 = sl * f2; a3 = sl * f3;
    }

    for (int p = start; p < end; p += 64) {
        const int n = min(64, end - p);
        int   mySrc = 0;
        float myW   = 0.f;
        if (lane < n) { mySrc = csr_src[p + lane]; myW = csr_w[p + lane]; }
        int j0 = 0;
        for (; j0 + 8 <= n; j0 += 8) {
            int sj[8]; float wj[8]; uint2 rj[8];
            #pragma unroll
            for (int j = 0; j < 8; j++) { sj[j] = __shfl(mySrc, j0 + j); wj[j] = __shfl(myW, j0 + j); }
            #pragma unroll
            for (int j = 0; j < 8; j++) rj[j] = *(const uint2*)(h + (size_t)sj[j] * 256 + lane * 4);
            #pragma unroll
            for (int j = 0; j < 8; j++) {
                float f0, f1, f2, f3; unp4(rj[j], f0, f1, f2, f3);
                a0 += wj[j] * f0; a1 += wj[j] * f1; a2 += wj[j] * f2; a3 += wj[j] * f3;
            }
        }
        for (; j0 < n; j0++) {
            int s = __shfl(mySrc, j0);
            float w = __shfl(myW, j0);
            uint2 rv = *(const uint2*)(h + (size_t)s * 256 + lane * 4);
            float f0, f1, f2, f3; unp4(rv, f0, f1, f2, f3);
            a0 += w * f0; a1 += w * f1; a2 += w * f2; a3 += w * f3;
        }
    }

    if (out_bf16 != nullptr) {
        uint2 o = {0u, 0u};
        if (lane < 50) {   // 50*4 = 200 real cols
            float4 bv = *(const float4*)(bias + lane * 4);
            u16 h0 = f2b(a0 + bv.x), h1 = f2b(a1 + bv.y), h2 = f2b(a2 + bv.z), h3 = f2b(a3 + bv.w);
            o.x = (uint32_t)h0 | ((uint32_t)h1 << 16);
            o.y = (uint32_t)h2 | ((uint32_t)h3 << 16);
        }
        *(uint2*)(out_bf16 + (size_t)node * 256 + lane * 4) = o;
    } else {
        float dot = 0.f, nn2 = 0.f;
        if (lane < 50) {
            float4 bv = *(const float4*)(bias + lane * 4);
            float4 dv = *(const float4*)(dhat + (node / 1000) * 200 + lane * 4);
            float v0 = a0 + bv.x, v1 = a1 + bv.y, v2 = a2 + bv.z, v3 = a3 + bv.w;
            dot = v0 * dv.x + v1 * dv.y + v2 * dv.z + v3 * dv.w;
            nn2 = v0 * v0 + v1 * v1 + v2 * v2 + v3 * v3;
        }
        #pragma unroll
        for (int off = 32; off; off >>= 1) {
            dot += __shfl_xor(dot, off, 64);
            nn2 += __shfl_xor(nn2, off, 64);
        }
        if (lane == 0) {
            float sim = dot / fmaxf(sqrtf(nn2), 1e-8f);
            out_sig[node] = 1.f / (1.f + expf(-sim));
        }
    }
}

// ---------- drug branch (tiny): one block per drug ----------
__global__ void drug_kernel(const float* __restrict__ drugF, const float* __restrict__ drugM,
                            const float* __restrict__ hW, const float* __restrict__ hb,
                            const float* __restrict__ m1W, const float* __restrict__ m1b,
                            const float* __restrict__ m2W, const float* __restrict__ m2b,
                            const float* __restrict__ l1W, const float* __restrict__ l1b,
                            const float* __restrict__ l2W, const float* __restrict__ l2b,
                            float* __restrict__ dhat) {
    const int b = blockIdx.x, tid = threadIdx.x;
    __shared__ float sF[1024], sM[1024], sT[256], s400[400], s200[200], sred[256];
    for (int k = tid; k < 1024; k += 256) { sF[k] = drugF[b * 1024 + k]; sM[k] = drugM[b * 1024 + k]; }
    __syncthreads();
    {
        float acc = m1b[tid];
        for (int k = 0; k < 1024; k++) acc += sM[k] * m1W[k * 256 + tid];
        sT[tid] = leakyf(acc);
    }
    float dfv = 0.f;
    if (tid < 200) {
        dfv = hb[tid];
        for (int k = 0; k < 1024; k++) dfv += sF[k] * hW[k * 200 + tid];
    }
    __syncthreads();
    if (tid < 200) {
        float acc = m2b[tid];
        for (int k = 0; k < 256; k++) acc += sT[k] * m2W[k * 200 + tid];
        s400[tid]       = leakyf(acc);
        s400[200 + tid] = leakyf(dfv);
    }
    __syncthreads();
    if (tid < 200) {
        float acc = l1b[tid];
        for (int k = 0; k < 400; k++) acc += s400[k] * l1W[k * 200 + tid];
        s200[tid] = leakyf(acc);
    }
    __syncthreads();
    float dv = 0.f;
    if (tid < 200) {
        dv = l2b[tid];
        for (int k = 0; k < 200; k++) dv += s200[k] * l2W[k * 200 + tid];
    }
    sred[tid] = (tid < 200) ? dv * dv : 0.f;
    __syncthreads();
    for (int off = 128; off; off >>= 1) {
        if (tid < off) sred[tid] += sred[tid + off];
        __syncthreads();
    }
    float nrm = fmaxf(sqrtf(sred[0]), 1e-8f);
    if (tid < 200) dhat[b * 200 + tid] = dv / nrm;
}

// ---------- launch ----------
extern "C" void kernel_launch(void* const* d_in, const int* in_sizes, int n_in,
                              void* d_out, int out_size, void* d_ws, size_t ws_size,
                              hipStream_t stream) {
    const float* PPI_x = (const float*)d_in[0];
    const float* PMF   = (const float*)d_in[1];
    const float* drugF = (const float*)d_in[2];
    const float* drugM = (const float*)d_in[3];
    const int*   eidx  = (const int*)d_in[4];
    const float* hpo_drug_W = (const float*)d_in[5];
    const float* hpo_drug_b = (const float*)d_in[6];
    const float* hpo_prot_W = (const float*)d_in[7];
    const float* hpo_prot_b = (const float*)d_in[8];
    const float* mp_W1 = (const float*)d_in[9];
    const float* mp_b1 = (const float*)d_in[10];
    const float* mp_W2 = (const float*)d_in[11];
    const float* mp_b2 = (const float*)d_in[12];
    const float* md_W1 = (const float*)d_in[13];
    const float* md_b1 = (const float*)d_in[14];
    const float* md_W2 = (const float*)d_in[15];
    const float* md_b2 = (const float*)d_in[16];
    const float* pl1_W = (const float*)d_in[17];
    const float* pl1_b = (const float*)d_in[18];
    const float* dl1_W = (const float*)d_in[19];
    const float* dl1_b = (const float*)d_in[20];
    const float* dl2_W = (const float*)d_in[21];
    const float* dl2_b = (const float*)d_in[22];
    const float* g1_W  = (const float*)d_in[23];
    const float* g1_b  = (const float*)d_in[24];
    const float* g2_W  = (const float*)d_in[25];
    const float* g2_b  = (const float*)d_in[26];

    char* wsp = (char*)d_ws;
    size_t off = 0;
    auto alloc = [&](size_t bytes) -> void* {
        size_t o = (off + 255) & ~(size_t)255;
        off = o + bytes;
        return (void*)(wsp + o);
    };

    u16* cb    = (u16*)alloc((size_t)NN * 512 * 2);   // leaky([px, pm])
    u16* t1    = (u16*)alloc((size_t)NN * 256 * 2);   // leaky(PMF@W1+b1); later y1
    u16* px2   = (u16*)alloc((size_t)NN * 256 * 2);
    u16* hbuf  = (u16*)alloc((size_t)NN * 256 * 2);
    float* part = (float*)alloc((size_t)2 * NN * 256 * 4);   // split-K partials (S=2)
    u16* Btmp1 = (u16*)alloc((size_t)256 * 8192 * 2);
    u16* Bthpo = (u16*)alloc((size_t)256 * 1024 * 2);
    u16* Btmp2 = (u16*)alloc((size_t)256 * 256 * 2);
    u16* Btpl1 = (u16*)alloc((size_t)256 * 512 * 2);
    u16* Btg1  = (u16*)alloc((size_t)256 * 256 * 2);
    u16* Btg2  = (u16*)alloc((size_t)256 * 256 * 2);
    float* bias_hpo = (float*)alloc(256 * 4);
    float* bias_m1  = (float*)alloc(256 * 4);
    float* bias_m2  = (float*)alloc(256 * 4);
    float* bias_pl  = (float*)alloc(256 * 4);
    float* zero256  = (float*)alloc(256 * 4);
    float* dhat     = (float*)alloc((size_t)BB * 200 * 4);
    int*   deg      = (int*)alloc((size_t)NN * 4);
    float* dinv     = (float*)alloc((size_t)NN * 4);
    int*   row_st   = (int*)alloc((size_t)(NN + 4) * 4);
    int*   cursor   = (int*)alloc((size_t)NN * 4);
    int*   csr_src  = (int*)alloc((size_t)EE * 4);
    float* csr_w    = (float*)alloc((size_t)EE * 4);

    u16* y1 = t1;           // alias (t1 dead after G3)
    const size_t PSTRIDE = (size_t)NN * 256;

    const int* e_src = eidx;
    const int* e_dst = eidx + EE;

    // weight conversions
    conv_wT<<<dim3(16, 4),  256, 0, stream>>>(hpo_prot_W, 200, 1024, 0, Bthpo, 1024, 0, 1024);
    conv_wT<<<dim3(128, 4), 256, 0, stream>>>(mp_W1,      256, 8192, 0, Btmp1, 8192, 0, 8192);
    conv_wT5<<<dim3(4, 4, 5), 256, 0, stream>>>(mp_W2, pl1_W, g1_W, g2_W, Btmp2, Btpl1, Btg1, Btg2);
    padvec5<<<5, 256, 0, stream>>>(hpo_prot_b, 200, bias_hpo,
                                   mp_b1,      256, bias_m1,
                                   mp_b2,      200, bias_m2,
                                   pl1_b,      200, bias_pl,
                                   nullptr,    0,   zero256);

    // drug branch
    drug_kernel<<<BB, 256, 0, stream>>>(drugF, drugM, hpo_drug_W, hpo_drug_b,
                                        md_W1, md_b1, md_W2, md_b2,
                                        dl1_W, dl1_b, dl2_W, dl2_b, dhat);

    const int MB = NN / 32;            // 250
    const int RG = (NN * 256) / 256;   // reduce grid

    // G1: cb[:,0:256] = leaky(PPI_x @ hpo_prot_W + b)   (K=1024, split-K=2)
    gemm_kernel<<<dim3(MB, 2), 256, 0, stream>>>(PPI_x, 1, 1024, Bthpo, 1024, 512, zero256, part, 2, 256, 0, PSTRIDE);
    reduce_k<<<RG, 256, 0, stream>>>(part, PSTRIDE, 2, bias_hpo, cb, 1, 512, 1);
    // G2: t1 = leaky(PMF @ mp_W1 + b1)   (K=8192, split-K=2)
    gemm_kernel<<<dim3(MB, 2), 256, 0, stream>>>(PMF, 1, 8192, Btmp1, 8192, 4096, zero256, part, 2, 256, 0, PSTRIDE);
    reduce_k<<<RG, 256, 0, stream>>>(part, PSTRIDE, 2, bias_m1, t1, 1, 256, 1);
    // G3: cb[:,256:512] = leaky(t1 @ mp_W2 + b2)   (K=256)
    gemm_kernel<<<dim3(MB, 1), 256, 0, stream>>>(t1, 0, 256, Btmp2, 256, 256, bias_m2, cb + 256, 1, 512, 1, 0);
    // G4: px2 = cb @ pl1_W + pl1_b   (K=512)
    gemm_kernel<<<dim3(MB, 1), 256, 0, stream>>>(cb, 0, 512, Btpl1, 512, 512, bias_pl, px2, 1, 256, 0, 0);

    // graph build
    zero_i32<<<(NN + 255) / 256, 256, 0, stream>>>(deg, NN);
    count_kernel<<<EE / 256, 256, 0, stream>>>(e_dst, deg);
    scan_kernel<<<1, 1024, 0, stream>>>(deg, row_st, cursor, dinv);
    fill_kernel<<<EE / 256, 256, 0, stream>>>(e_src, e_dst, cursor, dinv, csr_src, csr_w);

    // GCN layer 1
    gemm_kernel<<<dim3(MB, 1), 256, 0, stream>>>(px2, 0, 256, Btg1, 256, 256, zero256, hbuf, 1, 256, 0, 0);
    agg_kernel<<<NN / 4, 256, 0, stream>>>(hbuf, dinv, row_st, csr_src, csr_w, g1_b, y1, nullptr, nullptr);
    // GCN layer 2 + fused cosine/sigmoid
    gemm_kernel<<<dim3(MB, 1), 256, 0, stream>>>(y1, 0, 256, Btg2, 256, 256, zero256, hbuf, 1, 256, 0, 0);
    agg_kernel<<<NN / 4, 256, 0, stream>>>(hbuf, dinv, row_st, csr_src, csr_w, g2_b, nullptr, dhat, (float*)d_out);
}

// Round 3
// 822.527 us; speedup vs baseline: 1.1022x; 1.0936x over previous
//
#include <hip/hip_runtime.h>
#include <cstdint>
#include <cstddef>

// ---------- types / helpers ----------
typedef uint16_t u16;
typedef __bf16 bf16x8 __attribute__((ext_vector_type(8)));
typedef short  s16x8  __attribute__((ext_vector_type(8)));
typedef float  f32x4  __attribute__((ext_vector_type(4)));

__device__ __forceinline__ u16 f2b(float f) {
    union { float f; uint32_t u; } v; v.f = f;
    uint32_t u = v.u;
    uint32_t r = (u + 0x7FFFu + ((u >> 16) & 1u)) >> 16;   // RNE truncate to bf16
    return (u16)r;
}
__device__ __forceinline__ float b2f(u16 h) {
    union { uint32_t u; float f; } v; v.u = ((uint32_t)h) << 16;
    return v.f;
}
__device__ __forceinline__ float leakyf(float x) { return x > 0.f ? x : 0.2f * x; }
__device__ __forceinline__ void unp4(uint2 u, float& f0, float& f1, float& f2, float& f3) {
    union { uint32_t u; float f; } t;
    t.u = u.x << 16;          f0 = t.f;
    t.u = u.x & 0xffff0000u;  f1 = t.f;
    t.u = u.y << 16;          f2 = t.f;
    t.u = u.y & 0xffff0000u;  f3 = t.f;
}

static constexpr int NN = 8000;      // nodes
static constexpr int EE = 512000;    // edges
static constexpr int BB = 8;         // batch

// global_load_lds: LDS dest is wave-uniform base + lane*16 (guide §5); global src per-lane.
#define GLOAD_LDS16(gp, lp)                                                              \
    __builtin_amdgcn_global_load_lds((const __attribute__((address_space(1))) void*)(gp), \
                                     (__attribute__((address_space(3))) void*)(lp), 16, 0, 0)

// ---------- weight transpose+convert: W[k][n] (f32) -> Bt[n][k] (bf16), n padded to 256 ----------
__global__ void conv_wT(const float* __restrict__ W, int Wn, int rows, int rowOff,
                        u16* __restrict__ Bt, int Kpad, int kOff, int kSpan) {
    __shared__ u16 tile[64][65];
    const int kb = blockIdx.x * 64, nb = blockIdx.y * 64;
    const int tid = threadIdx.x;
    const int ln = tid & 63, lw = tid >> 6;
    #pragma unroll
    for (int r = 0; r < 16; r++) {
        int kk = kb + lw * 16 + r;
        int n  = nb + ln;
        float v = (kk < rows && n < Wn) ? W[(size_t)(rowOff + kk) * Wn + n] : 0.f;
        tile[ln][lw * 16 + r] = f2b(v);
    }
    __syncthreads();
    #pragma unroll
    for (int r = 0; r < 16; r++) {
        int nl = lw * 16 + r;
        int kk = kb + ln;
        if (kk < kSpan) Bt[(size_t)(nb + nl) * Kpad + kOff + kk] = tile[nl][ln];
    }
}

// merged small transposes: z selects one of 5 (all 200x(<=256) weights), grid (4,4,5)
__global__ void conv_wT5(const float* W_mp2, const float* W_pl1, const float* W_g1, const float* W_g2,
                         u16* Btmp2, u16* Btpl1, u16* Btg1, u16* Btg2) {
    __shared__ u16 tile[64][65];
    const float* W; int Wn, rows, rowOff; u16* Bt; int Kpad, kOff, kSpan;
    switch (blockIdx.z) {
        case 0: W = W_mp2; Wn = 200; rows = 256; rowOff = 0;   Bt = Btmp2; Kpad = 256; kOff = 0;   kSpan = 256; break;
        case 1: W = W_pl1; Wn = 200; rows = 200; rowOff = 0;   Bt = Btpl1; Kpad = 512; kOff = 0;   kSpan = 256; break;
        case 2: W = W_pl1; Wn = 200; rows = 200; rowOff = 200; Bt = Btpl1; Kpad = 512; kOff = 256; kSpan = 256; break;
        case 3: W = W_g1;  Wn = 200; rows = 200; rowOff = 0;   Bt = Btg1;  Kpad = 256; kOff = 0;   kSpan = 256; break;
        default:W = W_g2;  Wn = 200; rows = 200; rowOff = 0;   Bt = Btg2;  Kpad = 256; kOff = 0;   kSpan = 256; break;
    }
    const int kb = blockIdx.x * 64, nb = blockIdx.y * 64;
    const int tid = threadIdx.x;
    const int ln = tid & 63, lw = tid >> 6;
    #pragma unroll
    for (int r = 0; r < 16; r++) {
        int kk = kb + lw * 16 + r;
        int n  = nb + ln;
        float v = (kk < rows && n < Wn) ? W[(size_t)(rowOff + kk) * Wn + n] : 0.f;
        tile[ln][lw * 16 + r] = f2b(v);
    }
    __syncthreads();
    #pragma unroll
    for (int r = 0; r < 16; r++) {
        int nl = lw * 16 + r;
        int kk = kb + ln;
        if (kk < kSpan) Bt[(size_t)(nb + nl) * Kpad + kOff + kk] = tile[nl][ln];
    }
}

// pad 5 bias vectors to 256 floats each in one launch (src may be null -> zeros)
__global__ void padvec5(const float* p0, int n0, float* d0,
                        const float* p1, int n1, float* d1,
                        const float* p2, int n2, float* d2,
                        const float* p3, int n3, float* d3,
                        const float* p4, int n4, float* d4) {
    const float* p; int n; float* d;
    switch (blockIdx.x) {
        case 0: p = p0; n = n0; d = d0; break;
        case 1: p = p1; n = n1; d = d1; break;
        case 2: p = p2; n = n2; d = d2; break;
        case 3: p = p3; n = n3; d = d3; break;
        default: p = p4; n = n4; d = d4; break;
    }
    int i = threadIdx.x;
    d[i] = (p != nullptr && i < n) ? p[i] : 0.f;
}

__global__ void zero_i32(int* __restrict__ p, int n) {
    int i = blockIdx.x * 256 + threadIdx.x;
    if (i < n) p[i] = 0;
}

// ---------- MFMA GEMM: C[M,256] = A[M,K] @ Bt[256,K]^T (+ bias) ----------
// template BM in {32,64}. BN=256 (full width), BK=64. 256 threads = 4 waves,
// wave w -> cols [64w,64w+64). Round-0 single-buffer structure (measured best);
// B staged via global_load_lds w16 into linear LDS with XOR-granule source
// swizzle (m173; conflicts 6.1M->2.0M verified). A staged k-contiguous:
// 4 (BM=64) / 8 (BM=32) threads per row, each loading contiguous bytes ->
// full-line utilization within one instruction (was: 32 scattered lines/instr).
// Split-K via grid.y. cmode: 0=f32 out(+bias), 1=bf16 out(+bias), 2=f32 partial.
template<int BM>
__global__ __launch_bounds__(256) void gemm_kernel(
    const void* __restrict__ Ap, int a_is_f32, int lda,
    const u16* __restrict__ Bt, int K, int kLen,
    const float* __restrict__ bias,
    void* __restrict__ Cp, int cmode, int ldc, int do_leaky, size_t partStride) {
    constexpr int MREP = BM / 16;
    __shared__ u16 As[BM][72];             // padded rows: a-frag reads 2-way max
    __shared__ u16 Bs[16384];              // linear 256x64 bf16, swizzled granules
    const int tid  = threadIdx.x;
    const int m0   = blockIdx.x * BM;
    const int kStart = blockIdx.y * kLen;
    const int wave = tid >> 6, lane = tid & 63;
    const int q = lane >> 4, r = lane & 15;
    const int wn = wave * 64;

    f32x4 acc[MREP][4];
    #pragma unroll
    for (int i = 0; i < MREP; i++)
        #pragma unroll
        for (int j = 0; j < 4; j++) acc[i][j] = (f32x4){0, 0, 0, 0};

    for (int k0 = kStart; k0 < kStart + kLen; k0 += 64) {
        // ---- B: 8 async DMA loads per wave (in flight across A staging) ----
        #pragma unroll
        for (int c = 0; c < 8; ++c) {
            const int idx16 = c * 256 + tid;            // granule 0..2047
            const int row   = idx16 >> 3;               // 8 granules/row
            const int gs    = (idx16 & 7) ^ (row & 7);  // pre-swizzled source
            const u16* src  = Bt + (size_t)row * K + k0 + gs * 8;
            u16* dst = &Bs[0] + c * 2048 + wave * 512;  // wave-uniform base
            GLOAD_LDS16(src, dst);
        }
        // ---- A: k-contiguous staging (coalesced), cvt, ds_write ----
        if (BM == 64) {
            const int ar = tid >> 2, ac = (tid & 3) * 16;   // 4 thr/row, 64B each
            if (a_is_f32) {
                const float* A = (const float*)Ap + (size_t)(m0 + ar) * lda + k0 + ac;
                float4 f0 = *(const float4*)(A + 0);
                float4 f1 = *(const float4*)(A + 4);
                float4 f2 = *(const float4*)(A + 8);
                float4 f3 = *(const float4*)(A + 12);
                u16 h[16];
                h[0]=f2b(f0.x); h[1]=f2b(f0.y); h[2]=f2b(f0.z); h[3]=f2b(f0.w);
                h[4]=f2b(f1.x); h[5]=f2b(f1.y); h[6]=f2b(f1.z); h[7]=f2b(f1.w);
                h[8]=f2b(f2.x); h[9]=f2b(f2.y); h[10]=f2b(f2.z); h[11]=f2b(f2.w);
                h[12]=f2b(f3.x); h[13]=f2b(f3.y); h[14]=f2b(f3.z); h[15]=f2b(f3.w);
                *(uint4*)(&As[ar][ac])     = ((uint4*)h)[0];
                *(uint4*)(&As[ar][ac + 8]) = ((uint4*)h)[1];
            } else {
                const u16* A = (const u16*)Ap + (size_t)(m0 + ar) * lda + k0 + ac;
                uint4 u0 = *(const uint4*)(A + 0);
                uint4 u1 = *(const uint4*)(A + 8);
                *(uint4*)(&As[ar][ac])     = u0;
                *(uint4*)(&As[ar][ac + 8]) = u1;
            }
        } else {
            const int ar = tid >> 3, ac = (tid & 7) * 8;    // 8 thr/row, 32B each
            if (a_is_f32) {
                const float* A = (const float*)Ap + (size_t)(m0 + ar) * lda + k0 + ac;
                float4 f0 = *(const float4*)(A + 0);
                float4 f1 = *(const float4*)(A + 4);
                u16 h[8];
                h[0]=f2b(f0.x); h[1]=f2b(f0.y); h[2]=f2b(f0.z); h[3]=f2b(f0.w);
                h[4]=f2b(f1.x); h[5]=f2b(f1.y); h[6]=f2b(f1.z); h[7]=f2b(f1.w);
                *(uint4*)(&As[ar][ac]) = *(uint4*)h;
            } else {
                const u16* A = (const u16*)Ap + (size_t)(m0 + ar) * lda + k0 + ac;
                *(uint4*)(&As[ar][ac]) = *(const uint4*)A;
            }
        }
        __syncthreads();          // drains B DMA + A ds_write
        #pragma unroll
        for (int ks = 0; ks < 2; ks++) {
            const int kb = ks * 32 + q * 8;
            s16x8 a[MREP];
            #pragma unroll
            for (int m = 0; m < MREP; m++) a[m] = *(const s16x8*)(&As[m * 16 + r][kb]);
            const int swz  = ((ks << 2) + q) ^ (r & 7);     // granule XOR read
            const int boff = ((wn + r) << 7) + (swz << 4);  // bytes
            const char* BsC = (const char*)&Bs[0];
            s16x8 b[4];
            #pragma unroll
            for (int j = 0; j < 4; j++) b[j] = *(const s16x8*)(BsC + boff + j * 2048);
            #pragma unroll
            for (int m = 0; m < MREP; m++)
                #pragma unroll
                for (int j = 0; j < 4; j++)
                    acc[m][j] = __builtin_amdgcn_mfma_f32_16x16x32_bf16(
                        __builtin_bit_cast(bf16x8, a[m]), __builtin_bit_cast(bf16x8, b[j]),
                        acc[m][j], 0, 0, 0);
        }
        __syncthreads();
    }

    #pragma unroll
    for (int ti = 0; ti < MREP; ti++)
        #pragma unroll
        for (int tj = 0; tj < 4; tj++)
            #pragma unroll
            for (int reg = 0; reg < 4; reg++) {
                int gr = m0 + ti * 16 + q * 4 + reg;   // C/D: row = quad*4+reg
                int gc = wn + tj * 16 + r;             //      col = lane&15
                float v = acc[ti][tj][reg];
                if (cmode == 2) {
                    ((float*)Cp)[blockIdx.y * partStride + (size_t)gr * 256 + gc] = v;
                } else {
                    v += bias[gc];
                    if (do_leaky) v = leakyf(v);
                    if (cmode == 1) ((u16*)Cp)[(size_t)gr * ldc + gc] = f2b(v);
                    else            ((float*)Cp)[(size_t)gr * ldc + gc] = v;
                }
            }
}

// ---------- split-K reduce ----------
__global__ void reduce_k(const float* __restrict__ part, size_t partStride, int S,
                         const float* __restrict__ bias, void* __restrict__ out,
                         int out_bf16, int ldc, int do_leaky) {
    int i = blockIdx.x * 256 + threadIdx.x;    // over NN*256
    float v = 0.f;
    for (int s = 0; s < S; s++) v += part[s * partStride + i];
    int col = i & 255, row = i >> 8;
    v += bias[col];
    if (do_leaky) v = leakyf(v);
    if (out_bf16) ((u16*)out)[(size_t)row * ldc + col] = f2b(v);
    else          ((float*)out)[(size_t)row * ldc + col] = v;
}

// ---------- graph build ----------
__global__ void count_kernel(const int* __restrict__ dst, int* __restrict__ cnt) {
    int e = blockIdx.x * 256 + threadIdx.x;
    if (e < EE) atomicAdd(&cnt[dst[e]], 1);
}
// scan + dinv fused (single block, 1024 threads)
__global__ void scan_kernel(const int* __restrict__ cnt, int* __restrict__ row_start,
                            int* __restrict__ cursor, float* __restrict__ dinv) {
    __shared__ int part[1024];
    const int tid = threadIdx.x;
    int local[8];
    int s = 0;
    const int base = tid * 8;
    #pragma unroll
    for (int j = 0; j < 8; j++) { int idx = base + j; int v = (idx < NN) ? cnt[idx] : 0; local[j] = s; s += v; }
    part[tid] = s;
    __syncthreads();
    for (int off = 1; off < 1024; off <<= 1) {
        int v = (tid >= off) ? part[tid - off] : 0;
        __syncthreads();
        part[tid] += v;
        __syncthreads();
    }
    const int excl = (tid == 0) ? 0 : part[tid - 1];
    #pragma unroll
    for (int j = 0; j < 8; j++) {
        int idx = base + j;
        if (idx < NN) {
            int v = excl + local[j];
            row_start[idx] = v; cursor[idx] = v;
            dinv[idx] = rsqrtf((float)cnt[idx] + 2.0f);
        }
    }
    if (tid == 1023) row_start[NN] = part[1023];
}
__global__ void fill_kernel(const int* __restrict__ src, const int* __restrict__ dst,
                            int* __restrict__ cursor, const float* __restrict__ dinv,
                            int* __restrict__ csr_src, float* __restrict__ csr_w) {
    int e = blockIdx.x * 256 + threadIdx.x;
    if (e < EE) {
        int s = src[e], d = dst[e];
        int pos = atomicAdd(&cursor[d], 1);
        csr_src[pos] = s;
        csr_w[pos]   = dinv[s] * dinv[d];
    }
}

// ---------- GCN aggregation: wave-per-node, 4 cols/lane, 8-deep pipelined gathers ----------
// out_bf16 != null : layer-1 mode, writes y1[NN][256] bf16 (cols>=200 zero), bias = g1_b (200 raw)
// out_bf16 == null : layer-2 mode, fused cosine+sigmoid vs dhat -> out_sig[NN]
__global__ __launch_bounds__(256) void agg_kernel(
    const u16* __restrict__ h, const float* __restrict__ dinv,
    const int* __restrict__ row_start, const int* __restrict__ csr_src,
    const float* __restrict__ csr_w, const float* __restrict__ bias,
    u16* __restrict__ out_bf16, const float* __restrict__ dhat,
    float* __restrict__ out_sig) {
    const int wave = threadIdx.x >> 6, lane = threadIdx.x & 63;
    const int node = blockIdx.x * 4 + wave;
    const int start = row_start[node], end = row_start[node + 1];
    const float di = dinv[node];

    float a0, a1, a2, a3;
    {   // self loop: 2*dinv^2 * h[node]
        uint2 hv = *(const uint2*)(h + (size_t)node * 256 + lane * 4);
        float f0, f1, f2, f3; unp4(hv, f0, f1, f2, f3);
        float sl = 2.f * di * di;
        a0 = sl * f0; a1 = sl * f1; a2 = sl * f2; a3 = sl * f3;
    }

    for (int p = start; p < end; p += 64) {
        const int n = min(64, end - p);
        int   mySrc = 0;
        float myW   = 0.f;
        if (lane < n) { mySrc = csr_src[p + lane]; myW = csr_w[p + lane]; }
        int j0 = 0;
        for (; j0 + 8 <= n; j0 += 8) {
            int sj[8]; float wj[8]; uint2 rj[8];
            #pragma unroll
            for (int j = 0; j < 8; j++) { sj[j] = __shfl(mySrc, j0 + j); wj[j] = __shfl(myW, j0 + j); }
            #pragma unroll
            for (int j = 0; j < 8; j++) rj[j] = *(const uint2*)(h + (size_t)sj[j] * 256 + lane * 4);
            #pragma unroll
            for (int j = 0; j < 8; j++) {
                float f0, f1, f2, f3; unp4(rj[j], f0, f1, f2, f3);
                a0 += wj[j] * f0; a1 += wj[j] * f1; a2 += wj[j] * f2; a3 += wj[j] * f3;
            }
        }
        for (; j0 < n; j0++) {
            int s = __shfl(mySrc, j0);
            float w = __shfl(myW, j0);
            uint2 rv = *(const uint2*)(h + (size_t)s * 256 + lane * 4);
            float f0, f1, f2, f3; unp4(rv, f0, f1, f2, f3);
            a0 += w * f0; a1 += w * f1; a2 += w * f2; a3 += w * f3;
        }
    }

    if (out_bf16 != nullptr) {
        uint2 o = {0u, 0u};
        if (lane < 50) {   // 50*4 = 200 real cols
            float4 bv = *(const float4*)(bias + lane * 4);
            u16 h0 = f2b(a0 + bv.x), h1 = f2b(a1 + bv.y), h2 = f2b(a2 + bv.z), h3 = f2b(a3 + bv.w);
            o.x = (uint32_t)h0 | ((uint32_t)h1 << 16);
            o.y = (uint32_t)h2 | ((uint32_t)h3 << 16);
        }
        *(uint2*)(out_bf16 + (size_t)node * 256 + lane * 4) = o;
    } else {
        float dot = 0.f, nn2 = 0.f;
        if (lane < 50) {
            float4 bv = *(const float4*)(bias + lane * 4);
            float4 dv = *(const float4*)(dhat + (node / 1000) * 200 + lane * 4);
            float v0 = a0 + bv.x, v1 = a1 + bv.y, v2 = a2 + bv.z, v3 = a3 + bv.w;
            dot = v0 * dv.x + v1 * dv.y + v2 * dv.z + v3 * dv.w;
            nn2 = v0 * v0 + v1 * v1 + v2 * v2 + v3 * v3;
        }
        #pragma unroll
        for (int off = 32; off; off >>= 1) {
            dot += __shfl_xor(dot, off, 64);
            nn2 += __shfl_xor(nn2, off, 64);
        }
        if (lane == 0) {
            float sim = dot / fmaxf(sqrtf(nn2), 1e-8f);
            out_sig[node] = 1.f / (1.f + expf(-sim));
        }
    }
}

// ---------- drug branch (tiny): one block per drug ----------
__global__ void drug_kernel(const float* __restrict__ drugF, const float* __restrict__ drugM,
                            const float* __restrict__ hW, const float* __restrict__ hb,
                            const float* __restrict__ m1W, const float* __restrict__ m1b,
                            const float* __restrict__ m2W, const float* __restrict__ m2b,
                            const float* __restrict__ l1W, const float* __restrict__ l1b,
                            const float* __restrict__ l2W, const float* __restrict__ l2b,
                            float* __restrict__ dhat) {
    const int b = blockIdx.x, tid = threadIdx.x;
    __shared__ float sF[1024], sM[1024], sT[256], s400[400], s200[200], sred[256];
    for (int k = tid; k < 1024; k += 256) { sF[k] = drugF[b * 1024 + k]; sM[k] = drugM[b * 1024 + k]; }
    __syncthreads();
    {
        float acc = m1b[tid];
        for (int k = 0; k < 1024; k++) acc += sM[k] * m1W[k * 256 + tid];
        sT[tid] = leakyf(acc);
    }
    float dfv = 0.f;
    if (tid < 200) {
        dfv = hb[tid];
        for (int k = 0; k < 1024; k++) dfv += sF[k] * hW[k * 200 + tid];
    }
    __syncthreads();
    if (tid < 200) {
        float acc = m2b[tid];
        for (int k = 0; k < 256; k++) acc += sT[k] * m2W[k * 200 + tid];
        s400[tid]       = leakyf(acc);
        s400[200 + tid] = leakyf(dfv);
    }
    __syncthreads();
    if (tid < 200) {
        float acc = l1b[tid];
        for (int k = 0; k < 400; k++) acc += s400[k] * l1W[k * 200 + tid];
        s200[tid] = leakyf(acc);
    }
    __syncthreads();
    float dv = 0.f;
    if (tid < 200) {
        dv = l2b[tid];
        for (int k = 0; k < 200; k++) dv += s200[k] * l2W[k * 200 + tid];
    }
    sred[tid] = (tid < 200) ? dv * dv : 0.f;
    __syncthreads();
    for (int off = 128; off; off >>= 1) {
        if (tid < off) sred[tid] += sred[tid + off];
        __syncthreads();
    }
    float nrm = fmaxf(sqrtf(sred[0]), 1e-8f);
    if (tid < 200) dhat[b * 200 + tid] = dv / nrm;
}

// ---------- launch ----------
extern "C" void kernel_launch(void* const* d_in, const int* in_sizes, int n_in,
                              void* d_out, int out_size, void* d_ws, size_t ws_size,
                              hipStream_t stream) {
    const float* PPI_x = (const float*)d_in[0];
    const float* PMF   = (const float*)d_in[1];
    const float* drugF = (const float*)d_in[2];
    const float* drugM = (const float*)d_in[3];
    const int*   eidx  = (const int*)d_in[4];
    const float* hpo_drug_W = (const float*)d_in[5];
    const float* hpo_drug_b = (const float*)d_in[6];
    const float* hpo_prot_W = (const float*)d_in[7];
    const float* hpo_prot_b = (const float*)d_in[8];
    const float* mp_W1 = (const float*)d_in[9];
    const float* mp_b1 = (const float*)d_in[10];
    const float* mp_W2 = (const float*)d_in[11];
    const float* mp_b2 = (const float*)d_in[12];
    const float* md_W1 = (const float*)d_in[13];
    const float* md_b1 = (const float*)d_in[14];
    const float* md_W2 = (const float*)d_in[15];
    const float* md_b2 = (const float*)d_in[16];
    const float* pl1_W = (const float*)d_in[17];
    const float* pl1_b = (const float*)d_in[18];
    const float* dl1_W = (const float*)d_in[19];
    const float* dl1_b = (const float*)d_in[20];
    const float* dl2_W = (const float*)d_in[21];
    const float* dl2_b = (const float*)d_in[22];
    const float* g1_W  = (const float*)d_in[23];
    const float* g1_b  = (const float*)d_in[24];
    const float* g2_W  = (const float*)d_in[25];
    const float* g2_b  = (const float*)d_in[26];

    char* wsp = (char*)d_ws;
    size_t off = 0;
    auto alloc = [&](size_t bytes) -> void* {
        size_t o = (off + 255) & ~(size_t)255;
        off = o + bytes;
        return (void*)(wsp + o);
    };

    u16* cb    = (u16*)alloc((size_t)NN * 512 * 2);   // leaky([px, pm])
    u16* t1    = (u16*)alloc((size_t)NN * 256 * 2);   // leaky(PMF@W1+b1); later y1
    u16* px2   = (u16*)alloc((size_t)NN * 256 * 2);
    u16* hbuf  = (u16*)alloc((size_t)NN * 256 * 2);
    float* part = (float*)alloc((size_t)4 * NN * 256 * 4);   // split-K partials (S=4)
    u16* Btmp1 = (u16*)alloc((size_t)256 * 8192 * 2);
    u16* Bthpo = (u16*)alloc((size_t)256 * 1024 * 2);
    u16* Btmp2 = (u16*)alloc((size_t)256 * 256 * 2);
    u16* Btpl1 = (u16*)alloc((size_t)256 * 512 * 2);
    u16* Btg1  = (u16*)alloc((size_t)256 * 256 * 2);
    u16* Btg2  = (u16*)alloc((size_t)256 * 256 * 2);
    float* bias_hpo = (float*)alloc(256 * 4);
    float* bias_m1  = (float*)alloc(256 * 4);
    float* bias_m2  = (float*)alloc(256 * 4);
    float* bias_pl  = (float*)alloc(256 * 4);
    float* zero256  = (float*)alloc(256 * 4);
    float* dhat     = (float*)alloc((size_t)BB * 200 * 4);
    int*   deg      = (int*)alloc((size_t)NN * 4);
    float* dinv     = (float*)alloc((size_t)NN * 4);
    int*   row_st   = (int*)alloc((size_t)(NN + 4) * 4);
    int*   cursor   = (int*)alloc((size_t)NN * 4);
    int*   csr_src  = (int*)alloc((size_t)EE * 4);
    float* csr_w    = (float*)alloc((size_t)EE * 4);

    u16* y1 = t1;           // alias (t1 dead after G3)
    const size_t PSTRIDE = (size_t)NN * 256;

    const int* e_src = eidx;
    const int* e_dst = eidx + EE;

    // weight conversions
    conv_wT<<<dim3(16, 4),  256, 0, stream>>>(hpo_prot_W, 200, 1024, 0, Bthpo, 1024, 0, 1024);
    conv_wT<<<dim3(128, 4), 256, 0, stream>>>(mp_W1,      256, 8192, 0, Btmp1, 8192, 0, 8192);
    conv_wT5<<<dim3(4, 4, 5), 256, 0, stream>>>(mp_W2, pl1_W, g1_W, g2_W, Btmp2, Btpl1, Btg1, Btg2);
    padvec5<<<5, 256, 0, stream>>>(hpo_prot_b, 200, bias_hpo,
                                   mp_b1,      256, bias_m1,
                                   mp_b2,      200, bias_m2,
                                   pl1_b,      200, bias_pl,
                                   nullptr,    0,   zero256);

    // drug branch
    drug_kernel<<<BB, 256, 0, stream>>>(drugF, drugM, hpo_drug_W, hpo_drug_b,
                                        md_W1, md_b1, md_W2, md_b2,
                                        dl1_W, dl1_b, dl2_W, dl2_b, dhat);

    const int RG = (NN * 256) / 256;   // reduce grid

    // G1: cb[:,0:256] = leaky(PPI_x @ hpo_prot_W + b)   (K=1024, BM=64, split-K=4)
    gemm_kernel<64><<<dim3(125, 4), 256, 0, stream>>>(PPI_x, 1, 1024, Bthpo, 1024, 256, zero256, part, 2, 256, 0, PSTRIDE);
    reduce_k<<<RG, 256, 0, stream>>>(part, PSTRIDE, 4, bias_hpo, cb, 1, 512, 1);
    // G2: t1 = leaky(PMF @ mp_W1 + b1)   (K=8192, BM=64, split-K=4)
    gemm_kernel<64><<<dim3(125, 4), 256, 0, stream>>>(PMF, 1, 8192, Btmp1, 8192, 2048, zero256, part, 2, 256, 0, PSTRIDE);
    reduce_k<<<RG, 256, 0, stream>>>(part, PSTRIDE, 4, bias_m1, t1, 1, 256, 1);
    // G3: cb[:,256:512] = leaky(t1 @ mp_W2 + b2)   (K=256, BM=32)
    gemm_kernel<32><<<dim3(250, 1), 256, 0, stream>>>(t1, 0, 256, Btmp2, 256, 256, bias_m2, cb + 256, 1, 512, 1, 0);
    // G4: px2 = cb @ pl1_W + pl1_b   (K=512, BM=32)
    gemm_kernel<32><<<dim3(250, 1), 256, 0, stream>>>(cb, 0, 512, Btpl1, 512, 512, bias_pl, px2, 1, 256, 0, 0);

    // graph build
    zero_i32<<<(NN + 255) / 256, 256, 0, stream>>>(deg, NN);
    count_kernel<<<EE / 256, 256, 0, stream>>>(e_dst, deg);
    scan_kernel<<<1, 1024, 0, stream>>>(deg, row_st, cursor, dinv);
    fill_kernel<<<EE / 256, 256, 0, stream>>>(e_src, e_dst, cursor, dinv, csr_src, csr_w);

    // GCN layer 1
    gemm_kernel<32><<<dim3(250, 1), 256, 0, stream>>>(px2, 0, 256, Btg1, 256, 256, zero256, hbuf, 1, 256, 0, 0);
    agg_kernel<<<NN / 4, 256, 0, stream>>>(hbuf, dinv, row_st, csr_src, csr_w, g1_b, y1, nullptr, nullptr);
    // GCN layer 2 + fused cosine/sigmoid
    gemm_kernel<32><<<dim3(250, 1), 256, 0, stream>>>(y1, 0, 256, Btg2, 256, 256, zero256, hbuf, 1, 256, 0, 0);
    agg_kernel<<<NN / 4, 256, 0, stream>>>(hbuf, dinv, row_st, csr_src, csr_w, g2_b, nullptr, dhat, (float*)d_out);
}